// Round 13
// baseline (248.077 us; speedup 1.0000x reference)
//
#include <hip/hip_runtime.h>
#include <hip/hip_bf16.h>
#include <hip/hip_fp16.h>

#define NN 100000
#define NE 1200000
#define NG 512
#define NBK ((NN + 511) / 512)     // 196 dst buckets of 512 nodes
#define CAP 8192                    // ebuf slots per bucket (>> max bucket load)
#define SBATCH 4096                 // edges per sort block
#define EPB (SBATCH / 256)          // edges per thread
#define SA_BLOCKS ((NE + SBATCH - 1) / SBATCH)   // 293
#define TILES ((NN + 63) / 64)                    // 1563

// ---------------- CSR build ----------------
__global__ void k_binitF(int* gcur) {
    int b = blockIdx.x * blockDim.x + threadIdx.x;
    if (b < NBK) gcur[b] = b * CAP;
}

// sortA body: per-block LDS histogram + chunk reservation + dense record write
__device__ __forceinline__ void sortA_body(
    const int* __restrict__ srcA, const int* __restrict__ dstA, int e,
    int* gcur, uint2* __restrict__ ebuf, int bid, int* smemInt) {
    int* cnt = smemInt;
    int* base = smemInt + NBK;
    const int t = threadIdx.x;
    const int i0 = bid * SBATCH;
    for (int b = t; b < NBK; b += 256) cnt[b] = 0;
    __syncthreads();
#pragma unroll
    for (int k = 0; k < EPB; ++k) {
        int i = i0 + k * 256 + t;
        if (i < e) atomicAdd(&cnt[dstA[i] >> 9], 1);
    }
    __syncthreads();
    for (int b = t; b < NBK; b += 256) {
        int c = cnt[b];
        base[b] = c ? atomicAdd(&gcur[b], c) : 0;
        cnt[b] = 0;
    }
    __syncthreads();
#pragma unroll
    for (int k = 0; k < EPB; ++k) {
        int i = i0 + k * 256 + t;
        if (i < e) {
            int d = dstA[i], s = srcA[i];
            int b = d >> 9;
            int off = atomicAdd(&cnt[b], 1);
            int slot = base[b] + off;
            if (slot < (b + 1) * CAP)   // overflow guard (never expected)
                ebuf[slot] = make_uint2((unsigned)s, (unsigned)d);
        }
    }
}

// per-bucket dst histogram from bucket-grouped records (LDS counters), +1 self-loop
__global__ __launch_bounds__(256) void k_hist2(
    const uint2* __restrict__ ebuf, const int* __restrict__ gcur,
    int* __restrict__ cnt, int n) {
    __shared__ int c512[512];
    const int b = blockIdx.x;
    const int d0 = b << 9;
    const int hi = min(n - d0, 512);
    for (int j = threadIdx.x; j < 512; j += 256) c512[j] = 0;
    __syncthreads();
    const int beg = b * CAP, end = gcur[b];
    for (int i = beg + threadIdx.x; i < end; i += 256)
        atomicAdd(&c512[(int)ebuf[i].y - d0], 1);
    __syncthreads();
    for (int j = threadIdx.x; j < hi; j += 256) cnt[d0 + j] = c512[j] + 1;
}

__global__ void k_scan1(const int* __restrict__ cnt, int n, int* ex, int* blkSum) {
    __shared__ int s[1024];
    int i = blockIdx.x * 1024 + threadIdx.x;
    int v = (i < n) ? cnt[i] : 0;
    s[threadIdx.x] = v;
    __syncthreads();
    for (int off = 1; off < 1024; off <<= 1) {
        int t = (threadIdx.x >= off) ? s[threadIdx.x - off] : 0;
        __syncthreads();
        s[threadIdx.x] += t;
        __syncthreads();
    }
    if (i < n) ex[i] = s[threadIdx.x] - v;   // exclusive within block
    if (threadIdx.x == 1023) blkSum[blockIdx.x] = s[1023];
}

__global__ void k_scan2(const int* __restrict__ blkSum, int nb, int* blkOff, int* totalOut) {
    __shared__ int s[128];
    int t = threadIdx.x;
    int v = (t < nb) ? blkSum[t] : 0;
    s[t] = v;
    __syncthreads();
    for (int off = 1; off < 128; off <<= 1) {
        int x = (t >= off) ? s[t - off] : 0;
        __syncthreads();
        s[t] += x;
        __syncthreads();
    }
    if (t < nb) blkOff[t] = s[t] - v;
    if (t == 127) *totalOut = s[127];  // row_ptr[N] = total edge count
}

__global__ void k_scan3(int* row_ptr, const int* __restrict__ blkOff, int n) {
    int i = blockIdx.x * blockDim.x + threadIdx.x;
    if (i < n) row_ptr[i] += blkOff[i >> 10];
}

// pass B: block per bucket, LDS cursors, self-loop in slot 0 of each row
__global__ __launch_bounds__(512) void k_sortB2(
    const uint2* __restrict__ ebuf, const int* __restrict__ gcur,
    const int* __restrict__ row_ptr, int n, int* __restrict__ col) {
    __shared__ int cur[512];
    const int b = blockIdx.x;
    const int d0 = b << 9;
    const int hi = min(n - d0, 512);
    for (int j = threadIdx.x; j < hi; j += 512) {
        int rp = row_ptr[d0 + j];
        col[rp] = d0 + j;           // self-loop first
        cur[j] = rp + 1;
    }
    __syncthreads();
    const int beg = b * CAP, end = gcur[b];
    for (int i = beg + threadIdx.x; i < end; i += 512) {
        uint2 r = ebuf[i];
        int pos = atomicAdd(&cur[(int)r.y - d0], 1);
        col[pos] = (int)r.x;
    }
}

// ---------------- GEMM body (KC=32 sequential chunks, LDS 17920B) ----------------
#define XP 36
#define WP 68
#define SMEM_FLOATS (64 * XP + 32 * WP)   // 4480 floats = 17920 B

template <int K, bool HIN>
__device__ __forceinline__ void gemm_body(
    const float* __restrict__ Xf, const __half* __restrict__ Xh,
    const float* __restrict__ W,
    const float* __restrict__ a_src, const float* __restrict__ a_dst,
    __half* __restrict__ H, float* __restrict__ ssrc, float* __restrict__ sdst,
    int n, int tile, float* __restrict__ Xs, float* __restrict__ Ws) {
    constexpr int KC = 32;
    constexpr int NC = K / KC;
    const int tid = threadIdx.x;
    const int row0 = tile * 64;
    const int tx = tid & 15, ty = tid >> 4;
    float acc[4][4] = {};

    for (int c = 0; c < NC; ++c) {
        if (c) __syncthreads();
        // stage W chunk (KC x 64): 512 float4s
        for (int i = tid; i < KC * 16; i += 256) {
            int k = i >> 4, c4 = i & 15;
            float4 v = reinterpret_cast<const float4*>(W + (size_t)(c * KC + k) * 64)[c4];
            *reinterpret_cast<float4*>(&Ws[k * WP + c4 * 4]) = v;
        }
        // stage X chunk (64 x KC): 512 slots of 4 floats
        for (int i = tid; i < 64 * 8; i += 256) {
            int r = i >> 3, c4 = i & 7;
            int row = row0 + r;
            float4 v = make_float4(0.f, 0.f, 0.f, 0.f);
            if (row < n) {
                if constexpr (HIN) {
                    float2 raw = reinterpret_cast<const float2*>(Xh + (size_t)row * K + c * KC)[c4];
                    const __half2* ph = reinterpret_cast<const __half2*>(&raw);
                    float2 lo = __half22float2(ph[0]), hi = __half22float2(ph[1]);
                    v = make_float4(lo.x, lo.y, hi.x, hi.y);
                } else {
                    v = reinterpret_cast<const float4*>(Xf + (size_t)row * K + c * KC)[c4];
                }
            }
            *reinterpret_cast<float4*>(&Xs[r * XP + c4 * 4]) = v;
        }
        __syncthreads();

        for (int k = 0; k < KC; k += 4) {
            float4 xv[4], wv[4];
#pragma unroll
            for (int r = 0; r < 4; ++r)
                xv[r] = *reinterpret_cast<const float4*>(&Xs[(ty * 4 + r) * XP + k]);
#pragma unroll
            for (int j = 0; j < 4; ++j)
                wv[j] = *reinterpret_cast<const float4*>(&Ws[(k + j) * WP + tx * 4]);
#pragma unroll
            for (int r = 0; r < 4; ++r) {
                const float* xp = reinterpret_cast<const float*>(&xv[r]);
#pragma unroll
                for (int j = 0; j < 4; ++j) {
                    const float* wp = reinterpret_cast<const float*>(&wv[j]);
#pragma unroll
                    for (int cc = 0; cc < 4; ++cc) acc[r][cc] += xp[j] * wp[cc];
                }
            }
        }
    }

    float4 av = reinterpret_cast<const float4*>(a_src)[tx];
    float4 dv = reinterpret_cast<const float4*>(a_dst)[tx];
#pragma unroll
    for (int r = 0; r < 4; ++r) {
        int row = row0 + ty * 4 + r;
        if (row < n) {
            float2 packed;
            *reinterpret_cast<__half2*>(&packed.x) = __floats2half2_rn(acc[r][0], acc[r][1]);
            *reinterpret_cast<__half2*>(&packed.y) = __floats2half2_rn(acc[r][2], acc[r][3]);
            reinterpret_cast<float2*>(H + (size_t)row * 64)[tx] = packed;
            float ps = acc[r][0] * av.x + acc[r][1] * av.y + acc[r][2] * av.z + acc[r][3] * av.w;
            float pd = acc[r][0] * dv.x + acc[r][1] * dv.y + acc[r][2] * dv.z + acc[r][3] * dv.w;
#pragma unroll
            for (int off = 1; off < 16; off <<= 1) {
                ps += __shfl_xor(ps, off);
                pd += __shfl_xor(pd, off);
            }
            if (tx == 0) {
                ssrc[row] = ps;
                sdst[row] = pd;
            }
        }
    }
}

// combined: blocks [0, TILES) run layer-0 GEMM; the rest run sortA
__global__ __launch_bounds__(256) void k_g0sA(
    const int* __restrict__ srcA, const int* __restrict__ dstA,
    int* gcur, uint2* __restrict__ ebuf,
    const float* __restrict__ Xf, const float* __restrict__ W,
    const float* __restrict__ a_src, const float* __restrict__ a_dst,
    __half* __restrict__ H, float* __restrict__ ssrc, float* __restrict__ sdst, int n) {
    __shared__ float smem[SMEM_FLOATS];
    if (blockIdx.x < TILES) {
        gemm_body<128, false>(Xf, nullptr, W, a_src, a_dst, H, ssrc, sdst, n,
                              blockIdx.x, smem, smem + 64 * XP);
    } else {
        sortA_body(srcA, dstA, NE, gcur, ebuf, blockIdx.x - TILES,
                   reinterpret_cast<int*>(smem));
    }
}

template <int K, bool HIN>
__global__ __launch_bounds__(256) void k_gemm_att(
    const float* __restrict__ Xf, const __half* __restrict__ Xh,
    const float* __restrict__ W,
    const float* __restrict__ a_src, const float* __restrict__ a_dst,
    __half* __restrict__ H, float* __restrict__ ssrc, float* __restrict__ sdst, int n) {
    __shared__ float smem[SMEM_FLOATS];
    gemm_body<K, HIN>(Xf, Xh, W, a_src, a_dst, H, ssrc, sdst, n,
                      blockIdx.x, smem, smem + 64 * XP);
}

// ---------------- fused softmax + aggregation (2 dsts per wave) ----------------
// phase 2: 2 groups x 16 lanes per dst, 4-deep unroll -> 16 rows in flight/wave
__global__ __launch_bounds__(256) void k_agg5(
    const float2* __restrict__ H2, const float* __restrict__ ssrc,
    const float* __restrict__ sdst, const int* __restrict__ row_ptr,
    const int* __restrict__ col, const float4* __restrict__ bias4,
    float2* __restrict__ Yh2, int n) {
    const int wave = threadIdx.x >> 6, lane = threadIdx.x & 63;
    const int hf = lane >> 5, hl = lane & 31;
    const int base = blockIdx.x * 8 + wave * 2;
    const int dst = base + hf;

    int beg = 0, end = 0;
    if (dst < n) { beg = row_ptr[dst]; end = row_ptr[dst + 1]; }
    int deg = end - beg;
    int dmax = max(deg, __shfl_xor(deg, 32));

    if (dmax <= 32) {
        float sd = (dst < n) ? sdst[dst] : 0.f;
        int s_l = 0;
        float e = -INFINITY;
        if (hl < deg) {
            s_l = col[beg + hl];
            e = ssrc[s_l] + sd;
            e = (e > 0.f) ? e : 0.2f * e;
        }
        float m = e;
#pragma unroll
        for (int off = 16; off; off >>= 1) m = fmaxf(m, __shfl_xor(m, off));
        float w_l = (hl < deg) ? __expf(e - m) : 0.f;
        float den = w_l;
#pragma unroll
        for (int off = 16; off; off >>= 1) den += __shfl_xor(den, off);

        const int grp = hl >> 4, fl = hl & 15;
        float4 acc = make_float4(0.f, 0.f, 0.f, 0.f);
        for (int jj = 0; jj < deg; jj += 8) {
            int j0 = jj + grp, j1 = jj + 2 + grp, j2 = jj + 4 + grp, j3 = jj + 6 + grp;
            int s0 = __shfl(s_l, hf * 32 + j0), s1 = __shfl(s_l, hf * 32 + j1);
            int s2 = __shfl(s_l, hf * 32 + j2), s3 = __shfl(s_l, hf * 32 + j3);
            float w0 = __shfl(w_l, hf * 32 + j0), w1 = __shfl(w_l, hf * 32 + j1);
            float w2 = __shfl(w_l, hf * 32 + j2), w3 = __shfl(w_l, hf * 32 + j3);
            if (j0 < deg) {
                float2 raw = H2[(size_t)s0 * 16 + fl];
                const __half2* ph = reinterpret_cast<const __half2*>(&raw);
                float2 lo = __half22float2(ph[0]), hi = __half22float2(ph[1]);
                acc.x += w0 * lo.x; acc.y += w0 * lo.y;
                acc.z += w0 * hi.x; acc.w += w0 * hi.y;
            }
            if (j1 < deg) {
                float2 raw = H2[(size_t)s1 * 16 + fl];
                const __half2* ph = reinterpret_cast<const __half2*>(&raw);
                float2 lo = __half22float2(ph[0]), hi = __half22float2(ph[1]);
                acc.x += w1 * lo.x; acc.y += w1 * lo.y;
                acc.z += w1 * hi.x; acc.w += w1 * hi.y;
            }
            if (j2 < deg) {
                float2 raw = H2[(size_t)s2 * 16 + fl];
                const __half2* ph = reinterpret_cast<const __half2*>(&raw);
                float2 lo = __half22float2(ph[0]), hi = __half22float2(ph[1]);
                acc.x += w2 * lo.x; acc.y += w2 * lo.y;
                acc.z += w2 * hi.x; acc.w += w2 * hi.y;
            }
            if (j3 < deg) {
                float2 raw = H2[(size_t)s3 * 16 + fl];
                const __half2* ph = reinterpret_cast<const __half2*>(&raw);
                float2 lo = __half22float2(ph[0]), hi = __half22float2(ph[1]);
                acc.x += w3 * lo.x; acc.y += w3 * lo.y;
                acc.z += w3 * hi.x; acc.w += w3 * hi.y;
            }
        }
        acc.x += __shfl_xor(acc.x, 16);
        acc.y += __shfl_xor(acc.y, 16);
        acc.z += __shfl_xor(acc.z, 16);
        acc.w += __shfl_xor(acc.w, 16);
        if (grp == 0 && dst < n) {
            float inv = 1.f / den;
            float4 b = bias4[fl];
            float ox = fmaxf(acc.x * inv + b.x, 0.f);
            float oy = fmaxf(acc.y * inv + b.y, 0.f);
            float oz = fmaxf(acc.z * inv + b.z, 0.f);
            float ow = fmaxf(acc.w * inv + b.w, 0.f);
            float2 packed;
            *reinterpret_cast<__half2*>(&packed.x) = __floats2half2_rn(ox, oy);
            *reinterpret_cast<__half2*>(&packed.y) = __floats2half2_rn(oz, ow);
            Yh2[(size_t)dst * 16 + fl] = packed;
        }
    } else {
        for (int h = 0; h < 2; ++h) {
            int d = base + h;
            if (d >= n) break;
            int bg = row_ptr[d], en = row_ptr[d + 1];
            float sdd = sdst[d];
            float m = -INFINITY, d2 = 0.f;
            for (int c = bg; c < en; c += 64) {
                int j = c + lane;
                float e = -INFINITY;
                if (j < en) {
                    e = ssrc[col[j]] + sdd;
                    e = (e > 0.f) ? e : 0.2f * e;
                }
                float cm = e;
#pragma unroll
                for (int off = 32; off; off >>= 1) cm = fmaxf(cm, __shfl_xor(cm, off));
                float nm = fmaxf(m, cm);
                float term = (j < en) ? __expf(e - nm) : 0.f;
#pragma unroll
                for (int off = 32; off; off >>= 1) term += __shfl_xor(term, off);
                d2 = d2 * __expf(m - nm) + term;
                m = nm;
            }
            const int g4 = lane >> 4, fl = lane & 15;
            float4 acc = make_float4(0.f, 0.f, 0.f, 0.f);
            for (int jj = 0; jj < en - bg; jj += 8) {
                int j0 = bg + jj + g4, j1 = bg + jj + 4 + g4;
                if (j0 < en) {
                    int s = col[j0];
                    float e = ssrc[s] + sdd;
                    e = (e > 0.f) ? e : 0.2f * e;
                    float wgt = __expf(e - m);
                    float2 raw = H2[(size_t)s * 16 + fl];
                    const __half2* ph = reinterpret_cast<const __half2*>(&raw);
                    float2 lo = __half22float2(ph[0]), hi = __half22float2(ph[1]);
                    acc.x += wgt * lo.x; acc.y += wgt * lo.y;
                    acc.z += wgt * hi.x; acc.w += wgt * hi.y;
                }
                if (j1 < en) {
                    int s = col[j1];
                    float e = ssrc[s] + sdd;
                    e = (e > 0.f) ? e : 0.2f * e;
                    float wgt = __expf(e - m);
                    float2 raw = H2[(size_t)s * 16 + fl];
                    const __half2* ph = reinterpret_cast<const __half2*>(&raw);
                    float2 lo = __half22float2(ph[0]), hi = __half22float2(ph[1]);
                    acc.x += wgt * lo.x; acc.y += wgt * lo.y;
                    acc.z += wgt * hi.x; acc.w += wgt * hi.y;
                }
            }
#pragma unroll
            for (int off = 16; off < 64; off <<= 1) {
                acc.x += __shfl_xor(acc.x, off);
                acc.y += __shfl_xor(acc.y, off);
                acc.z += __shfl_xor(acc.z, off);
                acc.w += __shfl_xor(acc.w, off);
            }
            if (g4 == 0) {
                float inv = 1.f / d2;
                float4 b = bias4[fl];
                float ox = fmaxf(acc.x * inv + b.x, 0.f);
                float oy = fmaxf(acc.y * inv + b.y, 0.f);
                float oz = fmaxf(acc.z * inv + b.z, 0.f);
                float ow = fmaxf(acc.w * inv + b.w, 0.f);
                float2 packed;
                *reinterpret_cast<__half2*>(&packed.x) = __floats2half2_rn(ox, oy);
                *reinterpret_cast<__half2*>(&packed.y) = __floats2half2_rn(oz, ow);
                Yh2[(size_t)d * 16 + fl] = packed;
            }
        }
    }
}

// ---------------- pooling boundaries + pool + FC ----------------
__global__ void k_gstart(const int* __restrict__ batch, int n, int* gs) {
    int g = blockIdx.x * blockDim.x + threadIdx.x;
    if (g > NG) return;
    int lo = 0, hi = n;
    while (lo < hi) {
        int mid = (lo + hi) >> 1;
        if (batch[mid] < g) lo = mid + 1; else hi = mid;
    }
    gs[g] = lo;
}

__global__ __launch_bounds__(256) void k_pool_fc(
    const float2* __restrict__ Yh2, const int* __restrict__ gs,
    const float* __restrict__ fcW, const float* __restrict__ fcb,
    float* __restrict__ out) {
    __shared__ float4 part[4][16];
    __shared__ float p[64];
    const int g = blockIdx.x, tid = threadIdx.x;
    const int wave = tid >> 6, lane = tid & 63;
    const int grp = lane >> 4, fl = lane & 15;
    const int b = gs[g], e = gs[g + 1];

    float4 acc = make_float4(0.f, 0.f, 0.f, 0.f);
    for (int r = b + wave * 4 + grp; r < e; r += 16) {
        float2 raw = Yh2[(size_t)r * 16 + fl];
        const __half2* ph = reinterpret_cast<const __half2*>(&raw);
        float2 lo = __half22float2(ph[0]), hi = __half22float2(ph[1]);
        acc.x += lo.x; acc.y += lo.y; acc.z += hi.x; acc.w += hi.y;
    }
#pragma unroll
    for (int off = 16; off < 64; off <<= 1) {
        acc.x += __shfl_xor(acc.x, off);
        acc.y += __shfl_xor(acc.y, off);
        acc.z += __shfl_xor(acc.z, off);
        acc.w += __shfl_xor(acc.w, off);
    }
    if (grp == 0) part[wave][fl] = acc;
    __syncthreads();
    if (tid < 16) {
        float4 s0 = part[0][tid], s1 = part[1][tid], s2 = part[2][tid], s3 = part[3][tid];
        float inv = 1.f / (float)((e - b) > 0 ? (e - b) : 1);
        p[tid * 4 + 0] = (s0.x + s1.x + s2.x + s3.x) * inv;
        p[tid * 4 + 1] = (s0.y + s1.y + s2.y + s3.y) * inv;
        p[tid * 4 + 2] = (s0.z + s1.z + s2.z + s3.z) * inv;
        p[tid * 4 + 3] = (s0.w + s1.w + s2.w + s3.w) * inv;
    }
    __syncthreads();
    if (tid < 32) {
        float accO = fcb[tid];
#pragma unroll
        for (int k = 0; k < 64; ++k) accO += p[k] * fcW[k * 32 + tid];
        out[g * 32 + tid] = accO;
    }
}

// ---------------- launch ----------------
extern "C" void kernel_launch(void* const* d_in, const int* in_sizes, int n_in,
                              void* d_out, int out_size, void* d_ws, size_t ws_size,
                              hipStream_t stream) {
    const float* x = (const float*)d_in[0];
    const int* ei = (const int*)d_in[1];
    const int* batch = (const int*)d_in[2];
    const float* W0 = (const float*)d_in[3];
    const float* as0 = (const float*)d_in[4];
    const float* ad0 = (const float*)d_in[5];
    const float* b0 = (const float*)d_in[6];
    const float* W1 = (const float*)d_in[7];
    const float* as1 = (const float*)d_in[8];
    const float* ad1 = (const float*)d_in[9];
    const float* b1 = (const float*)d_in[10];
    const float* W2 = (const float*)d_in[11];
    const float* as2 = (const float*)d_in[12];
    const float* ad2 = (const float*)d_in[13];
    const float* b2 = (const float*)d_in[14];
    const float* fcW = (const float*)d_in[15];
    const float* fcb = (const float*)d_in[16];
    float* out = (float*)d_out;

    char* w = (char*)d_ws;
    auto alloc = [&](size_t bytes) {
        void* p = (void*)w;
        w += (bytes + 255) & ~(size_t)255;
        return p;
    };
    int* cnt = (int*)alloc((size_t)NN * 4);
    int* row_ptr = (int*)alloc((size_t)(NN + 1) * 4);
    int* blkSum = (int*)alloc(512);
    int* blkOff = (int*)alloc(512);
    int* gcur = (int*)alloc((size_t)NBK * 4);
    int* col = (int*)alloc((size_t)(NE + NN) * 4);
    int* gs = (int*)alloc((size_t)(NG + 1) * 4);
    uint2* ebuf = (uint2*)alloc((size_t)NBK * CAP * 8);
    __half* Ha = (__half*)alloc((size_t)NN * 64 * 2);
    __half* Hb = (__half*)alloc((size_t)NN * 64 * 2);
    __half* Y = (__half*)alloc((size_t)NN * 64 * 2);
    float* ssA = (float*)alloc((size_t)NN * 4);
    float* sdA = (float*)alloc((size_t)NN * 4);
    float* ssB = (float*)alloc((size_t)NN * 4);
    float* sdB = (float*)alloc((size_t)NN * 4);

    const int* srcA = ei;
    const int* dstA = ei + NE;

    // bucket cursor init, then combined {layer-0 GEMM || sortA}
    k_binitF<<<1, 256, 0, stream>>>(gcur);
    k_g0sA<<<TILES + SA_BLOCKS, 256, 0, stream>>>(srcA, dstA, gcur, ebuf,
                                                  x, W0, as0, ad0, Ha, ssA, sdA, NN);
    // CSR build tail
    k_hist2<<<NBK, 256, 0, stream>>>(ebuf, gcur, cnt, NN);
    const int nb = (NN + 1023) / 1024;  // 98
    k_scan1<<<nb, 1024, 0, stream>>>(cnt, NN, row_ptr, blkSum);
    k_scan2<<<1, 128, 0, stream>>>(blkSum, nb, blkOff, row_ptr + NN);
    k_scan3<<<(NN + 255) / 256, 256, 0, stream>>>(row_ptr, blkOff, NN);
    k_sortB2<<<NBK, 512, 0, stream>>>(ebuf, gcur, row_ptr, NN, col);
    k_gstart<<<3, 256, 0, stream>>>(batch, NN, gs);

    const int agg_grid = (NN + 7) / 8;      // 4 waves x 2 dsts per block

    // layer 0 aggregation -> Hb(fp16 as layer-1 input)
    k_agg5<<<agg_grid, 256, 0, stream>>>((const float2*)Ha, ssA, sdA, row_ptr, col,
                                         (const float4*)b0, (float2*)Hb, NN);
    // layer 1
    k_gemm_att<64, true><<<TILES, 256, 0, stream>>>(nullptr, Hb, W1, as1, ad1,
                                                    Ha, ssB, sdB, NN);
    k_agg5<<<agg_grid, 256, 0, stream>>>((const float2*)Ha, ssB, sdB, row_ptr, col,
                                         (const float4*)b1, (float2*)Hb, NN);
    // layer 2
    k_gemm_att<64, true><<<TILES, 256, 0, stream>>>(nullptr, Hb, W2, as2, ad2,
                                                    Ha, ssA, sdA, NN);
    k_agg5<<<agg_grid, 256, 0, stream>>>((const float2*)Ha, ssA, sdA, row_ptr, col,
                                         (const float4*)b2, (float2*)Y, NN);

    // pool + FC
    k_pool_fc<<<NG, 256, 0, stream>>>((const float2*)Y, gs, fcW, fcb, out);
}

// Round 14
// 234.556 us; speedup vs baseline: 1.0576x; 1.0576x over previous
//
#include <hip/hip_runtime.h>
#include <hip/hip_bf16.h>
#include <hip/hip_fp16.h>

#define NN 100000
#define NE 1200000
#define NG 512
#define NBK ((NN + 511) / 512)     // 196 dst buckets of 512 nodes
#define CAP 8192                    // ebuf slots per bucket (>> max bucket load)
#define SBATCH 4096                 // edges per sort block
#define EPB (SBATCH / 256)          // edges per thread
#define SA_BLOCKS ((NE + SBATCH - 1) / SBATCH)   // 293
#define TILES ((NN + 63) / 64)                    // 1563

// ---------------- CSR build ----------------
__global__ void k_binitF(int* gcur) {
    int b = blockIdx.x * blockDim.x + threadIdx.x;
    if (b < NBK) gcur[b] = b * CAP;
}

// sortA body: per-block LDS histogram + chunk reservation + dense record write
__device__ __forceinline__ void sortA_body(
    const int* __restrict__ srcA, const int* __restrict__ dstA, int e,
    int* gcur, uint2* __restrict__ ebuf, int bid, int* smemInt) {
    int* cnt = smemInt;
    int* base = smemInt + NBK;
    const int t = threadIdx.x;
    const int i0 = bid * SBATCH;
    for (int b = t; b < NBK; b += 256) cnt[b] = 0;
    __syncthreads();
#pragma unroll
    for (int k = 0; k < EPB; ++k) {
        int i = i0 + k * 256 + t;
        if (i < e) atomicAdd(&cnt[dstA[i] >> 9], 1);
    }
    __syncthreads();
    for (int b = t; b < NBK; b += 256) {
        int c = cnt[b];
        base[b] = c ? atomicAdd(&gcur[b], c) : 0;
        cnt[b] = 0;
    }
    __syncthreads();
#pragma unroll
    for (int k = 0; k < EPB; ++k) {
        int i = i0 + k * 256 + t;
        if (i < e) {
            int d = dstA[i], s = srcA[i];
            int b = d >> 9;
            int off = atomicAdd(&cnt[b], 1);
            int slot = base[b] + off;
            if (slot < (b + 1) * CAP)   // overflow guard (never expected)
                ebuf[slot] = make_uint2((unsigned)s, (unsigned)d);
        }
    }
}

// block 0: bucket-level prefix (bstart) + row_ptr[NN]; blocks 1..3: gstart
__global__ __launch_bounds__(256) void k_bucketPfx(
    const int* __restrict__ gcur, int* __restrict__ bstart, int* __restrict__ row_ptr,
    const int* __restrict__ batch, int* __restrict__ gs, int n) {
    if (blockIdx.x == 0) {
        __shared__ int s[256];
        const int t = threadIdx.x;
        int v = 0;
        if (t < NBK) {
            int d0 = t << 9;
            int hi = min(n - d0, 512);
            int edges = min(gcur[t] - t * CAP, CAP);
            v = edges + hi;             // records + self-loops in this bucket
        }
        s[t] = v;
        __syncthreads();
        for (int off = 1; off < 256; off <<= 1) {
            int x = (t >= off) ? s[t - off] : 0;
            __syncthreads();
            s[t] += x;
            __syncthreads();
        }
        if (t < NBK) bstart[t] = s[t] - v;
        if (t == NBK - 1) row_ptr[n] = s[t];
    } else {
        int g = (blockIdx.x - 1) * 256 + threadIdx.x;
        if (g > NG) return;
        int lo = 0, hi = n;
        while (lo < hi) {
            int mid = (lo + hi) >> 1;
            if (batch[mid] < g) lo = mid + 1; else hi = mid;
        }
        gs[g] = lo;
    }
}

// per-bucket: LDS hist -> LDS scan -> row_ptr write + self-loop + record place
__global__ __launch_bounds__(512) void k_place(
    const uint2* __restrict__ ebuf, const int* __restrict__ gcur,
    const int* __restrict__ bstart, int* __restrict__ row_ptr,
    int* __restrict__ col, int n) {
    __shared__ int cnt[512];
    __shared__ int scn[512];
    const int b = blockIdx.x;
    const int d0 = b << 9;
    const int hi = min(n - d0, 512);
    const int t = threadIdx.x;
    cnt[t] = (t < hi) ? 1 : 0;          // self-loop
    __syncthreads();
    const int beg = b * CAP;
    const int end = min(gcur[b], beg + CAP);
    for (int i = beg + t; i < end; i += 512)
        atomicAdd(&cnt[(int)ebuf[i].y - d0], 1);
    __syncthreads();
    int v = cnt[t];
    scn[t] = v;
    __syncthreads();
    for (int off = 1; off < 512; off <<= 1) {
        int x = (t >= off) ? scn[t - off] : 0;
        __syncthreads();
        scn[t] += x;
        __syncthreads();
    }
    int rp = bstart[b] + scn[t] - v;    // exclusive
    if (t < hi) {
        row_ptr[d0 + t] = rp;
        col[rp] = d0 + t;               // self-loop first
        cnt[t] = rp + 1;                // reuse cnt as cursor
    }
    __syncthreads();
    for (int i = beg + t; i < end; i += 512) {
        uint2 r = ebuf[i];
        int pos = atomicAdd(&cnt[(int)r.y - d0], 1);
        col[pos] = (int)r.x;
    }
}

// ---------------- GEMM body (KC=32 sequential chunks, LDS 17920B) ----------------
#define XP 36
#define WP 68
#define SMEM_FLOATS (64 * XP + 32 * WP)   // 4480 floats = 17920 B

template <int K, bool HIN>
__device__ __forceinline__ void gemm_body(
    const float* __restrict__ Xf, const __half* __restrict__ Xh,
    const float* __restrict__ W,
    const float* __restrict__ a_src, const float* __restrict__ a_dst,
    __half* __restrict__ H, float* __restrict__ ssrc, float* __restrict__ sdst,
    int n, int tile, float* __restrict__ Xs, float* __restrict__ Ws) {
    constexpr int KC = 32;
    constexpr int NC = K / KC;
    const int tid = threadIdx.x;
    const int row0 = tile * 64;
    const int tx = tid & 15, ty = tid >> 4;
    float acc[4][4] = {};

    for (int c = 0; c < NC; ++c) {
        if (c) __syncthreads();
        for (int i = tid; i < KC * 16; i += 256) {
            int k = i >> 4, c4 = i & 15;
            float4 v = reinterpret_cast<const float4*>(W + (size_t)(c * KC + k) * 64)[c4];
            *reinterpret_cast<float4*>(&Ws[k * WP + c4 * 4]) = v;
        }
        for (int i = tid; i < 64 * 8; i += 256) {
            int r = i >> 3, c4 = i & 7;
            int row = row0 + r;
            float4 v = make_float4(0.f, 0.f, 0.f, 0.f);
            if (row < n) {
                if constexpr (HIN) {
                    float2 raw = reinterpret_cast<const float2*>(Xh + (size_t)row * K + c * KC)[c4];
                    const __half2* ph = reinterpret_cast<const __half2*>(&raw);
                    float2 lo = __half22float2(ph[0]), hi = __half22float2(ph[1]);
                    v = make_float4(lo.x, lo.y, hi.x, hi.y);
                } else {
                    v = reinterpret_cast<const float4*>(Xf + (size_t)row * K + c * KC)[c4];
                }
            }
            *reinterpret_cast<float4*>(&Xs[r * XP + c4 * 4]) = v;
        }
        __syncthreads();

        for (int k = 0; k < KC; k += 4) {
            float4 xv[4], wv[4];
#pragma unroll
            for (int r = 0; r < 4; ++r)
                xv[r] = *reinterpret_cast<const float4*>(&Xs[(ty * 4 + r) * XP + k]);
#pragma unroll
            for (int j = 0; j < 4; ++j)
                wv[j] = *reinterpret_cast<const float4*>(&Ws[(k + j) * WP + tx * 4]);
#pragma unroll
            for (int r = 0; r < 4; ++r) {
                const float* xp = reinterpret_cast<const float*>(&xv[r]);
#pragma unroll
                for (int j = 0; j < 4; ++j) {
                    const float* wp = reinterpret_cast<const float*>(&wv[j]);
#pragma unroll
                    for (int cc = 0; cc < 4; ++cc) acc[r][cc] += xp[j] * wp[cc];
                }
            }
        }
    }

    float4 av = reinterpret_cast<const float4*>(a_src)[tx];
    float4 dv = reinterpret_cast<const float4*>(a_dst)[tx];
#pragma unroll
    for (int r = 0; r < 4; ++r) {
        int row = row0 + ty * 4 + r;
        if (row < n) {
            float2 packed;
            *reinterpret_cast<__half2*>(&packed.x) = __floats2half2_rn(acc[r][0], acc[r][1]);
            *reinterpret_cast<__half2*>(&packed.y) = __floats2half2_rn(acc[r][2], acc[r][3]);
            reinterpret_cast<float2*>(H + (size_t)row * 64)[tx] = packed;
            float ps = acc[r][0] * av.x + acc[r][1] * av.y + acc[r][2] * av.z + acc[r][3] * av.w;
            float pd = acc[r][0] * dv.x + acc[r][1] * dv.y + acc[r][2] * dv.z + acc[r][3] * dv.w;
#pragma unroll
            for (int off = 1; off < 16; off <<= 1) {
                ps += __shfl_xor(ps, off);
                pd += __shfl_xor(pd, off);
            }
            if (tx == 0) {
                ssrc[row] = ps;
                sdst[row] = pd;
            }
        }
    }
}

// combined: blocks [0, SA_BLOCKS) run sortA, the rest run layer-0 GEMM
__global__ __launch_bounds__(256) void k_g0sA(
    const int* __restrict__ srcA, const int* __restrict__ dstA,
    int* gcur, uint2* __restrict__ ebuf,
    const float* __restrict__ Xf, const float* __restrict__ W,
    const float* __restrict__ a_src, const float* __restrict__ a_dst,
    __half* __restrict__ H, float* __restrict__ ssrc, float* __restrict__ sdst, int n) {
    __shared__ float smem[SMEM_FLOATS];
    if (blockIdx.x < SA_BLOCKS) {
        sortA_body(srcA, dstA, NE, gcur, ebuf, blockIdx.x, reinterpret_cast<int*>(smem));
    } else {
        gemm_body<128, false>(Xf, nullptr, W, a_src, a_dst, H, ssrc, sdst, n,
                              blockIdx.x - SA_BLOCKS, smem, smem + 64 * XP);
    }
}

template <int K, bool HIN>
__global__ __launch_bounds__(256) void k_gemm_att(
    const float* __restrict__ Xf, const __half* __restrict__ Xh,
    const float* __restrict__ W,
    const float* __restrict__ a_src, const float* __restrict__ a_dst,
    __half* __restrict__ H, float* __restrict__ ssrc, float* __restrict__ sdst, int n) {
    __shared__ float smem[SMEM_FLOATS];
    gemm_body<K, HIN>(Xf, Xh, W, a_src, a_dst, H, ssrc, sdst, n,
                      blockIdx.x, smem, smem + 64 * XP);
}

// ---------------- fused softmax + aggregation (2 dsts per wave) ----------------
__global__ __launch_bounds__(256) void k_agg5(
    const float2* __restrict__ H2, const float* __restrict__ ssrc,
    const float* __restrict__ sdst, const int* __restrict__ row_ptr,
    const int* __restrict__ col, const float4* __restrict__ bias4,
    float2* __restrict__ Yh2, int n) {
    const int wave = threadIdx.x >> 6, lane = threadIdx.x & 63;
    const int hf = lane >> 5, hl = lane & 31;
    const int base = blockIdx.x * 8 + wave * 2;
    const int dst = base + hf;

    int beg = 0, end = 0;
    if (dst < n) { beg = row_ptr[dst]; end = row_ptr[dst + 1]; }
    int deg = end - beg;
    int dmax = max(deg, __shfl_xor(deg, 32));

    if (dmax <= 32) {
        float sd = (dst < n) ? sdst[dst] : 0.f;
        int s_l = 0;
        float e = -INFINITY;
        if (hl < deg) {
            s_l = col[beg + hl];
            e = ssrc[s_l] + sd;
            e = (e > 0.f) ? e : 0.2f * e;
        }
        float m = e;
#pragma unroll
        for (int off = 16; off; off >>= 1) m = fmaxf(m, __shfl_xor(m, off));
        float w_l = (hl < deg) ? __expf(e - m) : 0.f;
        float den = w_l;
#pragma unroll
        for (int off = 16; off; off >>= 1) den += __shfl_xor(den, off);

        const int grp = hl >> 4, fl = hl & 15;
        float4 acc = make_float4(0.f, 0.f, 0.f, 0.f);
        for (int jj = 0; jj < deg; jj += 8) {
            int j0 = jj + grp, j1 = jj + 2 + grp, j2 = jj + 4 + grp, j3 = jj + 6 + grp;
            int s0 = __shfl(s_l, hf * 32 + j0), s1 = __shfl(s_l, hf * 32 + j1);
            int s2 = __shfl(s_l, hf * 32 + j2), s3 = __shfl(s_l, hf * 32 + j3);
            float w0 = __shfl(w_l, hf * 32 + j0), w1 = __shfl(w_l, hf * 32 + j1);
            float w2 = __shfl(w_l, hf * 32 + j2), w3 = __shfl(w_l, hf * 32 + j3);
            if (j0 < deg) {
                float2 raw = H2[(size_t)s0 * 16 + fl];
                const __half2* ph = reinterpret_cast<const __half2*>(&raw);
                float2 lo = __half22float2(ph[0]), hi = __half22float2(ph[1]);
                acc.x += w0 * lo.x; acc.y += w0 * lo.y;
                acc.z += w0 * hi.x; acc.w += w0 * hi.y;
            }
            if (j1 < deg) {
                float2 raw = H2[(size_t)s1 * 16 + fl];
                const __half2* ph = reinterpret_cast<const __half2*>(&raw);
                float2 lo = __half22float2(ph[0]), hi = __half22float2(ph[1]);
                acc.x += w1 * lo.x; acc.y += w1 * lo.y;
                acc.z += w1 * hi.x; acc.w += w1 * hi.y;
            }
            if (j2 < deg) {
                float2 raw = H2[(size_t)s2 * 16 + fl];
                const __half2* ph = reinterpret_cast<const __half2*>(&raw);
                float2 lo = __half22float2(ph[0]), hi = __half22float2(ph[1]);
                acc.x += w2 * lo.x; acc.y += w2 * lo.y;
                acc.z += w2 * hi.x; acc.w += w2 * hi.y;
            }
            if (j3 < deg) {
                float2 raw = H2[(size_t)s3 * 16 + fl];
                const __half2* ph = reinterpret_cast<const __half2*>(&raw);
                float2 lo = __half22float2(ph[0]), hi = __half22float2(ph[1]);
                acc.x += w3 * lo.x; acc.y += w3 * lo.y;
                acc.z += w3 * hi.x; acc.w += w3 * hi.y;
            }
        }
        acc.x += __shfl_xor(acc.x, 16);
        acc.y += __shfl_xor(acc.y, 16);
        acc.z += __shfl_xor(acc.z, 16);
        acc.w += __shfl_xor(acc.w, 16);
        if (grp == 0 && dst < n) {
            float inv = 1.f / den;
            float4 b = bias4[fl];
            float ox = fmaxf(acc.x * inv + b.x, 0.f);
            float oy = fmaxf(acc.y * inv + b.y, 0.f);
            float oz = fmaxf(acc.z * inv + b.z, 0.f);
            float ow = fmaxf(acc.w * inv + b.w, 0.f);
            float2 packed;
            *reinterpret_cast<__half2*>(&packed.x) = __floats2half2_rn(ox, oy);
            *reinterpret_cast<__half2*>(&packed.y) = __floats2half2_rn(oz, ow);
            Yh2[(size_t)dst * 16 + fl] = packed;
        }
    } else {
        for (int h = 0; h < 2; ++h) {
            int d = base + h;
            if (d >= n) break;
            int bg = row_ptr[d], en = row_ptr[d + 1];
            float sdd = sdst[d];
            float m = -INFINITY, d2 = 0.f;
            for (int c = bg; c < en; c += 64) {
                int j = c + lane;
                float e = -INFINITY;
                if (j < en) {
                    e = ssrc[col[j]] + sdd;
                    e = (e > 0.f) ? e : 0.2f * e;
                }
                float cm = e;
#pragma unroll
                for (int off = 32; off; off >>= 1) cm = fmaxf(cm, __shfl_xor(cm, off));
                float nm = fmaxf(m, cm);
                float term = (j < en) ? __expf(e - nm) : 0.f;
#pragma unroll
                for (int off = 32; off; off >>= 1) term += __shfl_xor(term, off);
                d2 = d2 * __expf(m - nm) + term;
                m = nm;
            }
            const int g4 = lane >> 4, fl = lane & 15;
            float4 acc = make_float4(0.f, 0.f, 0.f, 0.f);
            for (int jj = 0; jj < en - bg; jj += 8) {
                int j0 = bg + jj + g4, j1 = bg + jj + 4 + g4;
                if (j0 < en) {
                    int s = col[j0];
                    float e = ssrc[s] + sdd;
                    e = (e > 0.f) ? e : 0.2f * e;
                    float wgt = __expf(e - m);
                    float2 raw = H2[(size_t)s * 16 + fl];
                    const __half2* ph = reinterpret_cast<const __half2*>(&raw);
                    float2 lo = __half22float2(ph[0]), hi = __half22float2(ph[1]);
                    acc.x += wgt * lo.x; acc.y += wgt * lo.y;
                    acc.z += wgt * hi.x; acc.w += wgt * hi.y;
                }
                if (j1 < en) {
                    int s = col[j1];
                    float e = ssrc[s] + sdd;
                    e = (e > 0.f) ? e : 0.2f * e;
                    float wgt = __expf(e - m);
                    float2 raw = H2[(size_t)s * 16 + fl];
                    const __half2* ph = reinterpret_cast<const __half2*>(&raw);
                    float2 lo = __half22float2(ph[0]), hi = __half22float2(ph[1]);
                    acc.x += wgt * lo.x; acc.y += wgt * lo.y;
                    acc.z += wgt * hi.x; acc.w += wgt * hi.y;
                }
            }
#pragma unroll
            for (int off = 16; off < 64; off <<= 1) {
                acc.x += __shfl_xor(acc.x, off);
                acc.y += __shfl_xor(acc.y, off);
                acc.z += __shfl_xor(acc.z, off);
                acc.w += __shfl_xor(acc.w, off);
            }
            if (g4 == 0) {
                float inv = 1.f / d2;
                float4 b = bias4[fl];
                float ox = fmaxf(acc.x * inv + b.x, 0.f);
                float oy = fmaxf(acc.y * inv + b.y, 0.f);
                float oz = fmaxf(acc.z * inv + b.z, 0.f);
                float ow = fmaxf(acc.w * inv + b.w, 0.f);
                float2 packed;
                *reinterpret_cast<__half2*>(&packed.x) = __floats2half2_rn(ox, oy);
                *reinterpret_cast<__half2*>(&packed.y) = __floats2half2_rn(oz, ow);
                Yh2[(size_t)d * 16 + fl] = packed;
            }
        }
    }
}

// ---------------- pool + FC ----------------
__global__ __launch_bounds__(256) void k_pool_fc(
    const float2* __restrict__ Yh2, const int* __restrict__ gs,
    const float* __restrict__ fcW, const float* __restrict__ fcb,
    float* __restrict__ out) {
    __shared__ float4 part[4][16];
    __shared__ float p[64];
    const int g = blockIdx.x, tid = threadIdx.x;
    const int wave = tid >> 6, lane = tid & 63;
    const int grp = lane >> 4, fl = lane & 15;
    const int b = gs[g], e = gs[g + 1];

    float4 acc = make_float4(0.f, 0.f, 0.f, 0.f);
    for (int r = b + wave * 4 + grp; r < e; r += 16) {
        float2 raw = Yh2[(size_t)r * 16 + fl];
        const __half2* ph = reinterpret_cast<const __half2*>(&raw);
        float2 lo = __half22float2(ph[0]), hi = __half22float2(ph[1]);
        acc.x += lo.x; acc.y += lo.y; acc.z += hi.x; acc.w += hi.y;
    }
#pragma unroll
    for (int off = 16; off < 64; off <<= 1) {
        acc.x += __shfl_xor(acc.x, off);
        acc.y += __shfl_xor(acc.y, off);
        acc.z += __shfl_xor(acc.z, off);
        acc.w += __shfl_xor(acc.w, off);
    }
    if (grp == 0) part[wave][fl] = acc;
    __syncthreads();
    if (tid < 16) {
        float4 s0 = part[0][tid], s1 = part[1][tid], s2 = part[2][tid], s3 = part[3][tid];
        float inv = 1.f / (float)((e - b) > 0 ? (e - b) : 1);
        p[tid * 4 + 0] = (s0.x + s1.x + s2.x + s3.x) * inv;
        p[tid * 4 + 1] = (s0.y + s1.y + s2.y + s3.y) * inv;
        p[tid * 4 + 2] = (s0.z + s1.z + s2.z + s3.z) * inv;
        p[tid * 4 + 3] = (s0.w + s1.w + s2.w + s3.w) * inv;
    }
    __syncthreads();
    if (tid < 32) {
        float accO = fcb[tid];
#pragma unroll
        for (int k = 0; k < 64; ++k) accO += p[k] * fcW[k * 32 + tid];
        out[g * 32 + tid] = accO;
    }
}

// ---------------- launch ----------------
extern "C" void kernel_launch(void* const* d_in, const int* in_sizes, int n_in,
                              void* d_out, int out_size, void* d_ws, size_t ws_size,
                              hipStream_t stream) {
    const float* x = (const float*)d_in[0];
    const int* ei = (const int*)d_in[1];
    const int* batch = (const int*)d_in[2];
    const float* W0 = (const float*)d_in[3];
    const float* as0 = (const float*)d_in[4];
    const float* ad0 = (const float*)d_in[5];
    const float* b0 = (const float*)d_in[6];
    const float* W1 = (const float*)d_in[7];
    const float* as1 = (const float*)d_in[8];
    const float* ad1 = (const float*)d_in[9];
    const float* b1 = (const float*)d_in[10];
    const float* W2 = (const float*)d_in[11];
    const float* as2 = (const float*)d_in[12];
    const float* ad2 = (const float*)d_in[13];
    const float* b2 = (const float*)d_in[14];
    const float* fcW = (const float*)d_in[15];
    const float* fcb = (const float*)d_in[16];
    float* out = (float*)d_out;

    char* w = (char*)d_ws;
    auto alloc = [&](size_t bytes) {
        void* p = (void*)w;
        w += (bytes + 255) & ~(size_t)255;
        return p;
    };
    int* row_ptr = (int*)alloc((size_t)(NN + 1) * 4);
    int* bstart = (int*)alloc((size_t)NBK * 4);
    int* gcur = (int*)alloc((size_t)NBK * 4);
    int* col = (int*)alloc((size_t)(NE + NN) * 4);
    int* gs = (int*)alloc((size_t)(NG + 1) * 4);
    uint2* ebuf = (uint2*)alloc((size_t)NBK * CAP * 8);
    __half* Ha = (__half*)alloc((size_t)NN * 64 * 2);
    __half* Hb = (__half*)alloc((size_t)NN * 64 * 2);
    __half* Y = (__half*)alloc((size_t)NN * 64 * 2);
    float* ssA = (float*)alloc((size_t)NN * 4);
    float* sdA = (float*)alloc((size_t)NN * 4);
    float* ssB = (float*)alloc((size_t)NN * 4);
    float* sdB = (float*)alloc((size_t)NN * 4);

    const int* srcA = ei;
    const int* dstA = ei + NE;

    // bucket cursor init, then combined {sortA || layer-0 GEMM}
    k_binitF<<<1, 256, 0, stream>>>(gcur);
    k_g0sA<<<SA_BLOCKS + TILES, 256, 0, stream>>>(srcA, dstA, gcur, ebuf,
                                                  x, W0, as0, ad0, Ha, ssA, sdA, NN);
    // fused CSR tail: bucket prefix (+gstart), then per-bucket place
    k_bucketPfx<<<4, 256, 0, stream>>>(gcur, bstart, row_ptr, batch, gs, NN);
    k_place<<<NBK, 512, 0, stream>>>(ebuf, gcur, bstart, row_ptr, col, NN);

    const int agg_grid = (NN + 7) / 8;      // 4 waves x 2 dsts per block

    // layer 0 aggregation -> Hb(fp16 as layer-1 input)
    k_agg5<<<agg_grid, 256, 0, stream>>>((const float2*)Ha, ssA, sdA, row_ptr, col,
                                         (const float4*)b0, (float2*)Hb, NN);
    // layer 1
    k_gemm_att<64, true><<<TILES, 256, 0, stream>>>(nullptr, Hb, W1, as1, ad1,
                                                    Ha, ssB, sdB, NN);
    k_agg5<<<agg_grid, 256, 0, stream>>>((const float2*)Ha, ssB, sdB, row_ptr, col,
                                         (const float4*)b1, (float2*)Hb, NN);
    // layer 2
    k_gemm_att<64, true><<<TILES, 256, 0, stream>>>(nullptr, Hb, W2, as2, ad2,
                                                    Ha, ssA, sdA, NN);
    k_agg5<<<agg_grid, 256, 0, stream>>>((const float2*)Ha, ssA, sdA, row_ptr, col,
                                         (const float4*)b2, (float2*)Y, NN);

    // pool + FC
    k_pool_fc<<<NG, 256, 0, stream>>>((const float2*)Y, gs, fcW, fcb, out);
}